// Round 1
// baseline (3623.765 us; speedup 1.0000x reference)
//
#include <hip/hip_runtime.h>
#include <hip/hip_bf16.h>
#include <cstdint>
#include <cstddef>

// Problem constants (B,T,C,H,D) = (2, 2048, 4096, 32, 128)
#define BB 2
#define TT 2048
#define CC 4096
#define HH 32
#define DD 128
#define MM (BB*TT)   // 4096 rows for all GEMMs

typedef __bf16 bf16;
typedef __bf16 bf16x8 __attribute__((ext_vector_type(8)));
typedef __bf16 bf16x4 __attribute__((ext_vector_type(4)));
typedef float  f32x4  __attribute__((ext_vector_type(4)));

// ---------------------------------------------------------------------------
// GEMM: C[M=4096, N=4096] = A[M,K=4096] @ W[K,N], bf16 MFMA 16x16x32.
// Block tile 128x128, BK=32, 4 waves each doing a 64x64 quadrant (4x4 MFMA tiles).
// AMODE: 0 = A is fp32 (convert while staging), 1 = A is bf16.
// EPI:   0 = RoPE + bf16 store [M,C]   (Q and K projections)
//        1 = bf16 store transposed per head -> vt[B,H,D,T]   (V projection)
//        2 = fp32 store [M,C]          (output projection -> d_out)
// ---------------------------------------------------------------------------
template<int AMODE, int EPI>
__global__ __launch_bounds__(256, 2) void gemm_k(
    const void* __restrict__ Ap, const float* __restrict__ Bw,
    void* __restrict__ Out, const float* __restrict__ sinp,
    const float* __restrict__ cosp)
{
  constexpr int N = CC, K = CC;
  // pad rows to 40 elems (80 B): 16B-aligned b128 frag reads, worst 2-way bank alias (free)
  __shared__ bf16 Al[128][40];
  __shared__ bf16 Bl[128][40];   // transposed: Bl[n][k] = W[k0+k][n0+n]

  const int tid  = threadIdx.x;
  const int wave = tid >> 6, lane = tid & 63;
  const int lr   = lane & 15, quad = lane >> 4;
  const int m0   = blockIdx.y * 128, n0 = blockIdx.x * 128;
  const int wm   = (wave >> 1) * 64, wn = (wave & 1) * 64;

  f32x4 acc[4][4];
  #pragma unroll
  for (int i = 0; i < 4; i++)
    #pragma unroll
    for (int j = 0; j < 4; j++) acc[i][j] = f32x4{0.f, 0.f, 0.f, 0.f};

  for (int k0 = 0; k0 < K; k0 += 32) {
    __syncthreads();
    // ---- stage A tile [128 x 32] ----
    if (AMODE == 0) {
      const float* A = (const float*)Ap;
      #pragma unroll
      for (int it = 0; it < 4; it++) {
        int idx = (it * 256 + tid) * 4;
        int row = idx >> 5, col = idx & 31;
        const float4 v = *(const float4*)(A + (size_t)(m0 + row) * K + k0 + col);
        bf16x4 w; w[0] = (bf16)v.x; w[1] = (bf16)v.y; w[2] = (bf16)v.z; w[3] = (bf16)v.w;
        *(bf16x4*)&Al[row][col] = w;
      }
    } else {
      const bf16* A = (const bf16*)Ap;
      #pragma unroll
      for (int it = 0; it < 2; it++) {
        int idx = (it * 256 + tid) * 8;
        int row = idx >> 5, col = idx & 31;
        bf16x8 v = *(const bf16x8*)(A + (size_t)(m0 + row) * K + k0 + col);
        *(bf16x8*)&Al[row][col] = v;
      }
    }
    // ---- stage B tile [32 x 128], transposed into Bl[n][k] ----
    #pragma unroll
    for (int it = 0; it < 4; it++) {
      int idx  = (it * 256 + tid) * 4;
      int krow = idx >> 7, col = idx & 127;
      const float4 v = *(const float4*)(Bw + (size_t)(k0 + krow) * N + n0 + col);
      Bl[col + 0][krow] = (bf16)v.x;
      Bl[col + 1][krow] = (bf16)v.y;
      Bl[col + 2][krow] = (bf16)v.z;
      Bl[col + 3][krow] = (bf16)v.w;
    }
    __syncthreads();

    bf16x8 af[4], bfv[4];
    #pragma unroll
    for (int i = 0; i < 4; i++) af[i]  = *(const bf16x8*)&Al[wm + 16 * i + lr][quad * 8];
    #pragma unroll
    for (int j = 0; j < 4; j++) bfv[j] = *(const bf16x8*)&Bl[wn + 16 * j + lr][quad * 8];
    #pragma unroll
    for (int i = 0; i < 4; i++)
      #pragma unroll
      for (int j = 0; j < 4; j++)
        acc[i][j] = __builtin_amdgcn_mfma_f32_16x16x32_bf16(af[i], bfv[j], acc[i][j], 0, 0, 0);
  }

  // ---- epilogue: C/D layout col = lane&15, row = quad*4 + r ----
  #pragma unroll
  for (int i = 0; i < 4; i++) {
    int grow = m0 + wm + 16 * i + quad * 4;
    #pragma unroll
    for (int j = 0; j < 4; j++) {
      int gc = n0 + wn + 16 * j + lr;
      if (EPI == 0) {
        // RoPE: out[2i] = x[2i]c - x[2i+1]s ; out[2i+1] = x[2i+1]c + x[2i]s
        // pair partner (col^1) lives in lane^1, same quad/reg.
        bf16* outp = (bf16*)Out;
        int dh = gc & (DD - 1);
        float sgn = (gc & 1) ? 1.0f : -1.0f;
        #pragma unroll
        for (int r = 0; r < 4; r++) {
          float x  = acc[i][j][r];
          float xp = __shfl_xor(x, 1, 64);
          int t = (grow + r) & (TT - 1);
          float s = sinp[t * DD + dh];
          float c = cosp[t * DD + dh];
          outp[(size_t)(grow + r) * N + gc] = (bf16)(x * c + sgn * xp * s);
        }
      } else if (EPI == 1) {
        // store V transposed per head: vt[b][h][d][t]
        bf16* outp = (bf16*)Out;
        int hh = gc >> 7, dh = gc & (DD - 1);
        int bidx = grow >> 11, t = grow & (TT - 1);
        bf16x4 w;
        #pragma unroll
        for (int r = 0; r < 4; r++) w[r] = (bf16)acc[i][j][r];
        *(bf16x4*)(outp + (((size_t)bidx * HH + hh) * DD + dh) * TT + t) = w;
      } else {
        float* outp = (float*)Out;
        #pragma unroll
        for (int r = 0; r < 4; r++)
          outp[(size_t)(grow + r) * N + gc] = acc[i][j][r];
      }
    }
  }
}

// ---------------------------------------------------------------------------
// Flash attention: one wave per (b, h, 16 q-rows). KV tiles of 32 keys.
// QK^T: A-frag = Q rows (direct 16B global loads), B-frag = K rows (same layout).
// Online softmax per q-row (rows live across the 16 lanes of a quad-group).
// P (C-layout) -> LDS -> A-frag for PV. V read from vt[B,H,D,T] (contiguous t).
// ---------------------------------------------------------------------------
__global__ __launch_bounds__(64) void attn_k(
    const bf16* __restrict__ qb, const bf16* __restrict__ kb,
    const bf16* __restrict__ vt, bf16* __restrict__ ao)
{
  const int lane = threadIdx.x;
  const int lr = lane & 15, quad = lane >> 4;
  const int q0 = blockIdx.x * 16;
  const int h  = blockIdx.y, b = blockIdx.z;

  __shared__ bf16 Pl[16][40];

  bf16x8 qf[4];
  const bf16* qrow = qb + ((size_t)(b * TT + q0 + lr) * HH + h) * DD;
  #pragma unroll
  for (int ds = 0; ds < 4; ds++) qf[ds] = *(const bf16x8*)(qrow + ds * 32 + quad * 8);

  float m_r[4], l_r[4];
  f32x4 oacc[8];
  #pragma unroll
  for (int r = 0; r < 4; r++) { m_r[r] = -1e30f; l_r[r] = 0.f; }
  #pragma unroll
  for (int dc = 0; dc < 8; dc++) oacc[dc] = f32x4{0.f, 0.f, 0.f, 0.f};

  const int jt_max = (q0 + 15) >> 5;           // causal: only tiles with k0 <= q0+15
  const float sc = 0.08838834764831845f;       // 1/sqrt(128)

  for (int jt = 0; jt <= jt_max; jt++) {
    const int k0 = jt * 32;
    f32x4 s0 = {0.f,0.f,0.f,0.f}, s1 = {0.f,0.f,0.f,0.f};
    const bf16* kr0 = kb + ((size_t)(b * TT + k0 + lr) * HH + h) * DD;
    const bf16* kr1 = kr0 + (size_t)16 * HH * DD;
    #pragma unroll
    for (int ds = 0; ds < 4; ds++) {
      bf16x8 k0f = *(const bf16x8*)(kr0 + ds * 32 + quad * 8);
      bf16x8 k1f = *(const bf16x8*)(kr1 + ds * 32 + quad * 8);
      s0 = __builtin_amdgcn_mfma_f32_16x16x32_bf16(qf[ds], k0f, s0, 0, 0, 0);
      s1 = __builtin_amdgcn_mfma_f32_16x16x32_bf16(qf[ds], k1f, s1, 0, 0, 0);
    }
    const int qrbase = q0 + quad * 4;
    float p0[4], p1[4];
    #pragma unroll
    for (int r = 0; r < 4; r++) {
      float v0 = s0[r] * sc, v1 = s1[r] * sc;
      if (k0 + lr      > qrbase + r) v0 = -1e30f;   // causal mask (no-op on interior tiles)
      if (k0 + 16 + lr > qrbase + r) v1 = -1e30f;
      p0[r] = v0; p1[r] = v1;
    }
    __syncthreads();   // WAR: previous tile's Pl reads done before overwrite
    #pragma unroll
    for (int r = 0; r < 4; r++) {
      float mx = fmaxf(p0[r], p1[r]);
      #pragma unroll
      for (int off = 1; off < 16; off <<= 1) mx = fmaxf(mx, __shfl_xor(mx, off, 64));
      float mnew  = fmaxf(m_r[r], mx);
      float alpha = __expf(m_r[r] - mnew);
      float e0 = __expf(p0[r] - mnew);
      float e1 = __expf(p1[r] - mnew);
      float ps = e0 + e1;
      #pragma unroll
      for (int off = 1; off < 16; off <<= 1) ps += __shfl_xor(ps, off, 64);
      l_r[r] = l_r[r] * alpha + ps;
      m_r[r] = mnew;
      #pragma unroll
      for (int dc = 0; dc < 8; dc++) oacc[dc][r] *= alpha;
      Pl[quad * 4 + r][lr]      = (bf16)e0;
      Pl[quad * 4 + r][lr + 16] = (bf16)e1;
    }
    __syncthreads();   // Pl writes visible (C-layout -> A-layout round trip)
    bf16x8 pf = *(const bf16x8*)&Pl[lr][quad * 8];
    const bf16* vbase = vt + ((size_t)b * HH + h) * DD * TT + k0 + quad * 8;
    #pragma unroll
    for (int dc = 0; dc < 8; dc++) {
      bf16x8 vf = *(const bf16x8*)(vbase + (size_t)(dc * 16 + lr) * TT);
      oacc[dc] = __builtin_amdgcn_mfma_f32_16x16x32_bf16(pf, vf, oacc[dc], 0, 0, 0);
    }
  }

  float inv[4];
  #pragma unroll
  for (int r = 0; r < 4; r++) inv[r] = 1.0f / l_r[r];
  bf16* aor = ao + ((size_t)(b * TT + q0 + quad * 4) * HH + h) * DD + lr;
  #pragma unroll
  for (int dc = 0; dc < 8; dc++)
    #pragma unroll
    for (int r = 0; r < 4; r++)
      aor[(size_t)r * HH * DD + dc * 16] = (bf16)(oacc[dc][r] * inv[r]);
}

// ---------------------------------------------------------------------------
// inputs: 0 hidden_states fp32 [B,T,C], 1 sin fp32 [T,D], 2 cos fp32 [T,D],
//         3 mask_bias (unused - causal implemented analytically),
//         4 Wq, 5 Wk, 6 Wv, 7 Wo (fp32 [C,C])
// output: fp32 [B,T,C]
// ws: qb, kb (bf16 [B,T,H,D]), vt (bf16 [B,H,D,T]), ao (bf16 [B,T,H,D]) = 128 MB
// ---------------------------------------------------------------------------
extern "C" void kernel_launch(void* const* d_in, const int* in_sizes, int n_in,
                              void* d_out, int out_size, void* d_ws, size_t ws_size,
                              hipStream_t stream)
{
  const float* hs   = (const float*)d_in[0];
  const float* sinp = (const float*)d_in[1];
  const float* cosp = (const float*)d_in[2];
  const float* Wq   = (const float*)d_in[4];
  const float* Wk   = (const float*)d_in[5];
  const float* Wv   = (const float*)d_in[6];
  const float* Wo   = (const float*)d_in[7];

  const size_t NE = (size_t)MM * CC;
  bf16* qb = (bf16*)d_ws;
  bf16* kb = qb + NE;
  bf16* vt = kb + NE;
  bf16* ao = vt + NE;

  dim3 gg(CC / 128, MM / 128), gb(256);
  gemm_k<0, 0><<<gg, gb, 0, stream>>>(hs, Wq, qb, sinp, cosp);
  gemm_k<0, 0><<<gg, gb, 0, stream>>>(hs, Wk, kb, sinp, cosp);
  gemm_k<0, 1><<<gg, gb, 0, stream>>>(hs, Wv, vt, sinp, cosp);
  attn_k<<<dim3(TT / 16, HH, BB), dim3(64), 0, stream>>>(qb, kb, vt, ao);
  gemm_k<1, 2><<<gg, gb, 0, stream>>>(ao, Wo, d_out, sinp, cosp);
}

// Round 2
// 1757.331 us; speedup vs baseline: 2.0621x; 2.0621x over previous
//
#include <hip/hip_runtime.h>
#include <hip/hip_bf16.h>
#include <cstdint>
#include <cstddef>

// Problem constants (B,T,C,H,D) = (2, 2048, 4096, 32, 128)
#define BB 2
#define TT 2048
#define CC 4096
#define HH 32
#define DD 128
#define MM (BB*TT)   // 4096 rows for all GEMMs

typedef __bf16 bf16;
typedef __bf16 bf16x8 __attribute__((ext_vector_type(8)));
typedef __bf16 bf16x4 __attribute__((ext_vector_type(4)));
typedef float  f32x4  __attribute__((ext_vector_type(4)));

__device__ __forceinline__ void async_copy16(const bf16* g, bf16* l) {
  __builtin_amdgcn_global_load_lds(
      (const __attribute__((address_space(1))) void*)g,
      (__attribute__((address_space(3))) void*)l, 16, 0, 0);
}

// ---------------------------------------------------------------------------
// fp32 -> bf16 convert (hidden_states).  n/8 threads, each does 8 elems.
// ---------------------------------------------------------------------------
__global__ __launch_bounds__(256) void conv_k(const float* __restrict__ X,
                                              bf16* __restrict__ Y)
{
  const size_t i = ((size_t)blockIdx.x * 256 + threadIdx.x) * 8;
  const float4 a = *(const float4*)(X + i);
  const float4 b = *(const float4*)(X + i + 4);
  bf16x8 w;
  w[0] = (bf16)a.x; w[1] = (bf16)a.y; w[2] = (bf16)a.z; w[3] = (bf16)a.w;
  w[4] = (bf16)b.x; w[5] = (bf16)b.y; w[6] = (bf16)b.z; w[7] = (bf16)b.w;
  *(bf16x8*)(Y + i) = w;
}

// ---------------------------------------------------------------------------
// W [K,N] fp32 -> Wt [N,K] bf16.  64x64 tile through LDS.
// Pad LDS k-dim to 72 so the write-phase b128 reads stay 16B-aligned.
// ---------------------------------------------------------------------------
__global__ __launch_bounds__(256) void transpose_k(const float* __restrict__ W,
                                                   bf16* __restrict__ Wt)
{
  __shared__ bf16 Tl[64][72];
  const int tid = threadIdx.x;
  const int k0 = blockIdx.x * 64, n0 = blockIdx.y * 64;
  #pragma unroll
  for (int it = 0; it < 4; it++) {
    int idx = it * 256 + tid;          // 0..1023
    int kr  = idx >> 4;                // 0..63
    int nc  = (idx & 15) * 4;
    float4 v = *(const float4*)(W + (size_t)(k0 + kr) * CC + n0 + nc);
    Tl[nc + 0][kr] = (bf16)v.x;
    Tl[nc + 1][kr] = (bf16)v.y;
    Tl[nc + 2][kr] = (bf16)v.z;
    Tl[nc + 3][kr] = (bf16)v.w;
  }
  __syncthreads();
  #pragma unroll
  for (int it = 0; it < 2; it++) {
    int idx = it * 256 + tid;          // 0..511
    int nr  = idx >> 3;                // 0..63
    int kc  = (idx & 7) * 8;
    bf16x8 v = *(const bf16x8*)&Tl[nr][kc];
    *(bf16x8*)(Wt + (size_t)(n0 + nr) * CC + k0 + kc) = v;
  }
}

// ---------------------------------------------------------------------------
// GEMM: C[M,N=4096] = A[M,K] @ Bt[N,K]^T, both bf16, MFMA 16x16x32.
// m97 structure: 128x128 tile, BK=32, global_load_lds width-16 staging into
// unpadded [row][32] LDS, ds_read_b128 fragment reads.
// EPI: 0 = RoPE + bf16 [M,C]; 1 = bf16 transposed per head -> vt[B,H,D,T];
//      2 = fp32 [M,C] (final output)
// ---------------------------------------------------------------------------
template<int EPI>
__global__ __launch_bounds__(256) void gemm_k(
    const bf16* __restrict__ A, const bf16* __restrict__ Bt,
    void* __restrict__ Out, const float* __restrict__ sinp,
    const float* __restrict__ cosp)
{
  constexpr int N = CC, K = CC;
  __shared__ bf16 Al[128 * 32];
  __shared__ bf16 Bl[128 * 32];

  const int tid  = threadIdx.x;
  const int wave = tid >> 6, lane = tid & 63;
  const int lr   = lane & 15, quad = lane >> 4;
  const int m0   = blockIdx.y * 128, n0 = blockIdx.x * 128;
  const int wm   = (wave >> 1) * 64, wn = (wave & 1) * 64;

  // staging geometry: instruction s in {0,1}; chunk = s*4+wave covers rows
  // [chunk*16, chunk*16+16); lane i -> row chunk*16 + i/4, col (i&3)*8;
  // LDS dest = chunk*512 + lane*8 elements (wave-uniform base + lane*16 B).
  const int srow = lane >> 2;          // 0..15
  const int scol = (lane & 3) * 8;     // 0,8,16,24

  f32x4 acc[4][4];
  #pragma unroll
  for (int i = 0; i < 4; i++)
    #pragma unroll
    for (int j = 0; j < 4; j++) acc[i][j] = f32x4{0.f, 0.f, 0.f, 0.f};

  for (int k0 = 0; k0 < K; k0 += 32) {
    __syncthreads();   // previous iteration's frag reads done
    #pragma unroll
    for (int s = 0; s < 2; s++) {
      const int chunk = s * 4 + wave;
      const int row   = chunk * 16 + srow;
      async_copy16(A  + (size_t)(m0 + row) * K + k0 + scol, Al + chunk * 512 + lane * 8);
      async_copy16(Bt + (size_t)(n0 + row) * K + k0 + scol, Bl + chunk * 512 + lane * 8);
    }
    __syncthreads();   // compiler drains vmcnt(0) before s_barrier

    bf16x8 af[4], bfv[4];
    #pragma unroll
    for (int i = 0; i < 4; i++) af[i]  = *(const bf16x8*)&Al[(wm + 16 * i + lr) * 32 + quad * 8];
    #pragma unroll
    for (int j = 0; j < 4; j++) bfv[j] = *(const bf16x8*)&Bl[(wn + 16 * j + lr) * 32 + quad * 8];
    #pragma unroll
    for (int i = 0; i < 4; i++)
      #pragma unroll
      for (int j = 0; j < 4; j++)
        acc[i][j] = __builtin_amdgcn_mfma_f32_16x16x32_bf16(af[i], bfv[j], acc[i][j], 0, 0, 0);
  }

  // ---- epilogue: C/D layout col = lane&15, row = quad*4 + r ----
  #pragma unroll
  for (int i = 0; i < 4; i++) {
    int grow = m0 + wm + 16 * i + quad * 4;
    #pragma unroll
    for (int j = 0; j < 4; j++) {
      int gc = n0 + wn + 16 * j + lr;
      if (EPI == 0) {
        // RoPE: out[2i] = x[2i]c - x[2i+1]s ; out[2i+1] = x[2i+1]c + x[2i]s
        // pair partner (col^1) lives in lane^1, same quad/reg.
        bf16* outp = (bf16*)Out;
        int dh = gc & (DD - 1);
        float sgn = (gc & 1) ? 1.0f : -1.0f;
        #pragma unroll
        for (int r = 0; r < 4; r++) {
          float x  = acc[i][j][r];
          float xp = __shfl_xor(x, 1, 64);
          int t = (grow + r) & (TT - 1);
          float s = sinp[t * DD + dh];
          float c = cosp[t * DD + dh];
          outp[(size_t)(grow + r) * N + gc] = (bf16)(x * c + sgn * xp * s);
        }
      } else if (EPI == 1) {
        // store V transposed per head: vt[b][h][d][t]
        bf16* outp = (bf16*)Out;
        int hh = gc >> 7, dh = gc & (DD - 1);
        int bidx = grow >> 11, t = grow & (TT - 1);
        bf16x4 w;
        #pragma unroll
        for (int r = 0; r < 4; r++) w[r] = (bf16)acc[i][j][r];
        *(bf16x4*)(outp + (((size_t)bidx * HH + hh) * DD + dh) * TT + t) = w;
      } else {
        float* outp = (float*)Out;
        #pragma unroll
        for (int r = 0; r < 4; r++)
          outp[(size_t)(grow + r) * N + gc] = acc[i][j][r];
      }
    }
  }
}

// ---------------------------------------------------------------------------
// Flash attention: one wave per (b, h, 16 q-rows). KV tiles of 32 keys.
// ---------------------------------------------------------------------------
__global__ __launch_bounds__(64) void attn_k(
    const bf16* __restrict__ qb, const bf16* __restrict__ kb,
    const bf16* __restrict__ vt, bf16* __restrict__ ao)
{
  const int lane = threadIdx.x;
  const int lr = lane & 15, quad = lane >> 4;
  const int q0 = blockIdx.x * 16;
  const int h  = blockIdx.y, b = blockIdx.z;

  __shared__ bf16 Pl[16][40];

  bf16x8 qf[4];
  const bf16* qrow = qb + ((size_t)(b * TT + q0 + lr) * HH + h) * DD;
  #pragma unroll
  for (int ds = 0; ds < 4; ds++) qf[ds] = *(const bf16x8*)(qrow + ds * 32 + quad * 8);

  float m_r[4], l_r[4];
  f32x4 oacc[8];
  #pragma unroll
  for (int r = 0; r < 4; r++) { m_r[r] = -1e30f; l_r[r] = 0.f; }
  #pragma unroll
  for (int dc = 0; dc < 8; dc++) oacc[dc] = f32x4{0.f, 0.f, 0.f, 0.f};

  const int jt_max = (q0 + 15) >> 5;           // causal: only tiles with k0 <= q0+15
  const float sc = 0.08838834764831845f;       // 1/sqrt(128)

  for (int jt = 0; jt <= jt_max; jt++) {
    const int k0 = jt * 32;
    f32x4 s0 = {0.f,0.f,0.f,0.f}, s1 = {0.f,0.f,0.f,0.f};
    const bf16* kr0 = kb + ((size_t)(b * TT + k0 + lr) * HH + h) * DD;
    const bf16* kr1 = kr0 + (size_t)16 * HH * DD;
    #pragma unroll
    for (int ds = 0; ds < 4; ds++) {
      bf16x8 k0f = *(const bf16x8*)(kr0 + ds * 32 + quad * 8);
      bf16x8 k1f = *(const bf16x8*)(kr1 + ds * 32 + quad * 8);
      s0 = __builtin_amdgcn_mfma_f32_16x16x32_bf16(qf[ds], k0f, s0, 0, 0, 0);
      s1 = __builtin_amdgcn_mfma_f32_16x16x32_bf16(qf[ds], k1f, s1, 0, 0, 0);
    }
    const int qrbase = q0 + quad * 4;
    float p0[4], p1[4];
    #pragma unroll
    for (int r = 0; r < 4; r++) {
      float v0 = s0[r] * sc, v1 = s1[r] * sc;
      if (k0 + lr      > qrbase + r) v0 = -1e30f;   // causal mask
      if (k0 + 16 + lr > qrbase + r) v1 = -1e30f;
      p0[r] = v0; p1[r] = v1;
    }
    __syncthreads();   // WAR on Pl
    #pragma unroll
    for (int r = 0; r < 4; r++) {
      float mx = fmaxf(p0[r], p1[r]);
      #pragma unroll
      for (int off = 1; off < 16; off <<= 1) mx = fmaxf(mx, __shfl_xor(mx, off, 64));
      float mnew  = fmaxf(m_r[r], mx);
      float alpha = __expf(m_r[r] - mnew);
      float e0 = __expf(p0[r] - mnew);
      float e1 = __expf(p1[r] - mnew);
      float ps = e0 + e1;
      #pragma unroll
      for (int off = 1; off < 16; off <<= 1) ps += __shfl_xor(ps, off, 64);
      l_r[r] = l_r[r] * alpha + ps;
      m_r[r] = mnew;
      #pragma unroll
      for (int dc = 0; dc < 8; dc++) oacc[dc][r] *= alpha;
      Pl[quad * 4 + r][lr]      = (bf16)e0;
      Pl[quad * 4 + r][lr + 16] = (bf16)e1;
    }
    __syncthreads();   // Pl visible (C-layout -> A-layout round trip)
    bf16x8 pf = *(const bf16x8*)&Pl[lr][quad * 8];
    const bf16* vbase = vt + ((size_t)b * HH + h) * DD * TT + k0 + quad * 8;
    #pragma unroll
    for (int dc = 0; dc < 8; dc++) {
      bf16x8 vf = *(const bf16x8*)(vbase + (size_t)(dc * 16 + lr) * TT);
      oacc[dc] = __builtin_amdgcn_mfma_f32_16x16x32_bf16(pf, vf, oacc[dc], 0, 0, 0);
    }
  }

  float inv[4];
  #pragma unroll
  for (int r = 0; r < 4; r++) inv[r] = 1.0f / l_r[r];
  bf16* aor = ao + ((size_t)(b * TT + q0 + quad * 4) * HH + h) * DD + lr;
  #pragma unroll
  for (int dc = 0; dc < 8; dc++)
    #pragma unroll
    for (int r = 0; r < 4; r++)
      aor[(size_t)r * HH * DD + dc * 16] = (bf16)(oacc[dc][r] * inv[r]);
}

// ---------------------------------------------------------------------------
// inputs: 0 hs fp32 [B,T,C], 1 sin [T,D], 2 cos [T,D], 3 mask (unused),
//         4 Wq, 5 Wk, 6 Wv, 7 Wo fp32 [C,C]
// ws: Ab bf16 [M,C] 32MB | Wt bf16 [C,C] 32MB (reused 4x) |
//     qb kb vt ao bf16 32MB each  => 192 MB
// ---------------------------------------------------------------------------
extern "C" void kernel_launch(void* const* d_in, const int* in_sizes, int n_in,
                              void* d_out, int out_size, void* d_ws, size_t ws_size,
                              hipStream_t stream)
{
  const float* hs   = (const float*)d_in[0];
  const float* sinp = (const float*)d_in[1];
  const float* cosp = (const float*)d_in[2];
  const float* Wq   = (const float*)d_in[4];
  const float* Wk   = (const float*)d_in[5];
  const float* Wv   = (const float*)d_in[6];
  const float* Wo   = (const float*)d_in[7];

  const size_t NE = (size_t)MM * CC;
  bf16* Ab = (bf16*)d_ws;
  bf16* Wt = Ab + NE;
  bf16* qb = Wt + NE;
  bf16* kb = qb + NE;
  bf16* vt = kb + NE;
  bf16* ao = vt + NE;

  dim3 gg(CC / 128, MM / 128), gb(256);
  dim3 gt(CC / 64, CC / 64);

  conv_k<<<NE / (256 * 8), 256, 0, stream>>>(hs, Ab);

  transpose_k<<<gt, gb, 0, stream>>>(Wq, Wt);
  gemm_k<0><<<gg, gb, 0, stream>>>(Ab, Wt, qb, sinp, cosp);

  transpose_k<<<gt, gb, 0, stream>>>(Wk, Wt);
  gemm_k<0><<<gg, gb, 0, stream>>>(Ab, Wt, kb, sinp, cosp);

  transpose_k<<<gt, gb, 0, stream>>>(Wv, Wt);
  gemm_k<1><<<gg, gb, 0, stream>>>(Ab, Wt, vt, sinp, cosp);

  attn_k<<<dim3(TT / 16, HH, BB), dim3(64), 0, stream>>>(qb, kb, vt, ao);

  transpose_k<<<gt, gb, 0, stream>>>(Wo, Wt);
  gemm_k<2><<<gg, gb, 0, stream>>>(ao, Wt, d_out, sinp, cosp);
}

// Round 3
// 1438.065 us; speedup vs baseline: 2.5199x; 1.2220x over previous
//
#include <hip/hip_runtime.h>
#include <hip/hip_bf16.h>
#include <cstdint>
#include <cstddef>

// Problem constants (B,T,C,H,D) = (2, 2048, 4096, 32, 128)
#define BB 2
#define TT 2048
#define CC 4096
#define HH 32
#define DD 128
#define MM (BB*TT)   // 4096 rows for all GEMMs

typedef __bf16 bf16;
typedef __bf16 bf16x8 __attribute__((ext_vector_type(8)));
typedef __bf16 bf16x4 __attribute__((ext_vector_type(4)));
typedef float  f32x4  __attribute__((ext_vector_type(4)));

__device__ __forceinline__ void async_copy16(const bf16* g, bf16* l) {
  __builtin_amdgcn_global_load_lds(
      (const __attribute__((address_space(1))) void*)g,
      (__attribute__((address_space(3))) void*)l, 16, 0, 0);
}

// ---------------------------------------------------------------------------
// fp32 -> bf16 convert (hidden_states).
// ---------------------------------------------------------------------------
__global__ __launch_bounds__(256) void conv_k(const float* __restrict__ X,
                                              bf16* __restrict__ Y)
{
  const size_t i = ((size_t)blockIdx.x * 256 + threadIdx.x) * 8;
  const float4 a = *(const float4*)(X + i);
  const float4 b = *(const float4*)(X + i + 4);
  bf16x8 w;
  w[0] = (bf16)a.x; w[1] = (bf16)a.y; w[2] = (bf16)a.z; w[3] = (bf16)a.w;
  w[4] = (bf16)b.x; w[5] = (bf16)b.y; w[6] = (bf16)b.z; w[7] = (bf16)b.w;
  *(bf16x8*)(Y + i) = w;
}

// ---------------------------------------------------------------------------
// W [K,N] fp32 -> Wt [N,K] bf16.  64x64 tile through LDS.
// ---------------------------------------------------------------------------
__global__ __launch_bounds__(256) void transpose_k(const float* __restrict__ W,
                                                   bf16* __restrict__ Wt)
{
  __shared__ bf16 Tl[64][72];
  const int tid = threadIdx.x;
  const int k0 = blockIdx.x * 64, n0 = blockIdx.y * 64;
  #pragma unroll
  for (int it = 0; it < 4; it++) {
    int idx = it * 256 + tid;          // 0..1023
    int kr  = idx >> 4;                // 0..63
    int nc  = (idx & 15) * 4;
    float4 v = *(const float4*)(W + (size_t)(k0 + kr) * CC + n0 + nc);
    Tl[nc + 0][kr] = (bf16)v.x;
    Tl[nc + 1][kr] = (bf16)v.y;
    Tl[nc + 2][kr] = (bf16)v.z;
    Tl[nc + 3][kr] = (bf16)v.w;
  }
  __syncthreads();
  #pragma unroll
  for (int it = 0; it < 2; it++) {
    int idx = it * 256 + tid;          // 0..511
    int nr  = idx >> 3;                // 0..63
    int kc  = (idx & 7) * 8;
    bf16x8 v = *(const bf16x8*)&Tl[nr][kc];
    *(bf16x8*)(Wt + (size_t)(n0 + nr) * CC + k0 + kc) = v;
  }
}

// ---------------------------------------------------------------------------
// GEMM: C[M,N=4096] = A[M,K] @ Bt[N,K]^T, both bf16, MFMA 16x16x32.
// m97 structure: 128x128 tile, BK=32, global_load_lds width-16 staging.
// EPI: 0 = RoPE + bf16 [M,C]; 1 = bf16 transposed per head -> vt[B,H,D,T];
//      2 = fp32 [M,C] (final output)
// ---------------------------------------------------------------------------
template<int EPI>
__global__ __launch_bounds__(256) void gemm_k(
    const bf16* __restrict__ A, const bf16* __restrict__ Bt,
    void* __restrict__ Out, const float* __restrict__ sinp,
    const float* __restrict__ cosp)
{
  constexpr int N = CC, K = CC;
  __shared__ bf16 Al[128 * 32];
  __shared__ bf16 Bl[128 * 32];

  const int tid  = threadIdx.x;
  const int wave = tid >> 6, lane = tid & 63;
  const int lr   = lane & 15, quad = lane >> 4;
  const int m0   = blockIdx.y * 128, n0 = blockIdx.x * 128;
  const int wm   = (wave >> 1) * 64, wn = (wave & 1) * 64;

  const int srow = lane >> 2;          // 0..15
  const int scol = (lane & 3) * 8;     // 0,8,16,24

  f32x4 acc[4][4];
  #pragma unroll
  for (int i = 0; i < 4; i++)
    #pragma unroll
    for (int j = 0; j < 4; j++) acc[i][j] = f32x4{0.f, 0.f, 0.f, 0.f};

  for (int k0 = 0; k0 < K; k0 += 32) {
    __syncthreads();
    #pragma unroll
    for (int s = 0; s < 2; s++) {
      const int chunk = s * 4 + wave;
      const int row   = chunk * 16 + srow;
      async_copy16(A  + (size_t)(m0 + row) * K + k0 + scol, Al + chunk * 512 + lane * 8);
      async_copy16(Bt + (size_t)(n0 + row) * K + k0 + scol, Bl + chunk * 512 + lane * 8);
    }
    __syncthreads();

    bf16x8 af[4], bfv[4];
    #pragma unroll
    for (int i = 0; i < 4; i++) af[i]  = *(const bf16x8*)&Al[(wm + 16 * i + lr) * 32 + quad * 8];
    #pragma unroll
    for (int j = 0; j < 4; j++) bfv[j] = *(const bf16x8*)&Bl[(wn + 16 * j + lr) * 32 + quad * 8];
    #pragma unroll
    for (int i = 0; i < 4; i++)
      #pragma unroll
      for (int j = 0; j < 4; j++)
        acc[i][j] = __builtin_amdgcn_mfma_f32_16x16x32_bf16(af[i], bfv[j], acc[i][j], 0, 0, 0);
  }

  // ---- epilogue: C/D layout col = lane&15, row = quad*4 + r ----
  #pragma unroll
  for (int i = 0; i < 4; i++) {
    int grow = m0 + wm + 16 * i + quad * 4;
    #pragma unroll
    for (int j = 0; j < 4; j++) {
      int gc = n0 + wn + 16 * j + lr;
      if (EPI == 0) {
        bf16* outp = (bf16*)Out;
        int dh = gc & (DD - 1);
        float sgn = (gc & 1) ? 1.0f : -1.0f;
        #pragma unroll
        for (int r = 0; r < 4; r++) {
          float x  = acc[i][j][r];
          float xp = __shfl_xor(x, 1, 64);
          int t = (grow + r) & (TT - 1);
          float s = sinp[t * DD + dh];
          float c = cosp[t * DD + dh];
          outp[(size_t)(grow + r) * N + gc] = (bf16)(x * c + sgn * xp * s);
        }
      } else if (EPI == 1) {
        bf16* outp = (bf16*)Out;
        int hh = gc >> 7, dh = gc & (DD - 1);
        int bidx = grow >> 11, t = grow & (TT - 1);
        bf16x4 w;
        #pragma unroll
        for (int r = 0; r < 4; r++) w[r] = (bf16)acc[i][j][r];
        *(bf16x4*)(outp + (((size_t)bidx * HH + hh) * DD + dh) * TT + t) = w;
      } else {
        float* outp = (float*)Out;
        #pragma unroll
        for (int r = 0; r < 4; r++)
          outp[(size_t)(grow + r) * N + gc] = acc[i][j][r];
      }
    }
  }
}

// ---------------------------------------------------------------------------
// Flash attention v2: 4 waves/block, 64 q-rows/block (16 per wave),
// 64-key K/V tiles staged cooperatively in LDS via global_load_lds.
// XOR-swizzled LDS (16B granule) to kill bank conflicts on frag reads.
// All waves run all of the block's tiles (masked tiles give e=0) so the
// per-tile __syncthreads stay convergent under causal imbalance.
// ---------------------------------------------------------------------------
__global__ __launch_bounds__(256) void attn_k(
    const bf16* __restrict__ qb, const bf16* __restrict__ kb,
    const bf16* __restrict__ vt, bf16* __restrict__ ao)
{
  const int tid  = threadIdx.x;
  const int wave = tid >> 6, lane = tid & 63;
  const int lr   = lane & 15, quad = lane >> 4;
  const int qblk = blockIdx.x * 64;
  const int q0   = qblk + wave * 16;       // this wave's 16 q-rows
  const int h    = blockIdx.y, b = blockIdx.z;

  // Kl row k (256B): slot s (16B) holds K[k][(s ^ (k&15))*8 ..]
  // Vl row d (128B): slot s (16B) holds Vt[d][(s ^ (d&7))*8 ..]   (cols = t)
  __shared__ bf16 Kl[64 * 128];
  __shared__ bf16 Vl[128 * 64];
  __shared__ bf16 Pl[4][16][72];           // per-wave P, padded to 72 (16B-aligned rows)

  // Q fragments (A-layout): lane holds Q[q0+lr][quad*8+j + 32*ds]
  bf16x8 qf[4];
  const bf16* qrow = qb + ((size_t)(b * TT + q0 + lr) * HH + h) * DD;
  #pragma unroll
  for (int ds = 0; ds < 4; ds++) qf[ds] = *(const bf16x8*)(qrow + ds * 32 + quad * 8);

  float m_r[4], l_r[4];
  f32x4 oacc[8];
  #pragma unroll
  for (int r = 0; r < 4; r++) { m_r[r] = -1e30f; l_r[r] = 0.f; }
  #pragma unroll
  for (int dc = 0; dc < 8; dc++) oacc[dc] = f32x4{0.f, 0.f, 0.f, 0.f};

  const int jt_end = (qblk + 63) >> 6;     // inclusive
  const float sc = 0.08838834764831845f;   // 1/sqrt(128)

  const bf16* kbase = kb + ((size_t)(b * TT) * HH + h) * DD;
  const bf16* vbase = vt + ((size_t)b * HH + h) * DD * TT;

  // staging geometry (per wave, 4 instrs each for K and V):
  const int k_row_in  = lane >> 4;         // 0..3   (4 rows of 256B per chunk)
  const int k_slot    = lane & 15;
  const int v_row_in  = lane >> 3;         // 0..7   (8 rows of 128B per chunk)
  const int v_slot    = lane & 7;

  for (int jt = 0; jt <= jt_end; jt++) {
    const int k0 = jt * 64;
    __syncthreads();                       // WAR: Kl/Vl reads of prev tile done
    #pragma unroll
    for (int s = 0; s < 4; s++) {
      const int ch   = s * 4 + wave;       // 0..15
      const int krow = ch * 4 + k_row_in;  // 0..63
      const int kcol = (k_slot ^ (krow & 15)) * 8;
      async_copy16(kbase + (size_t)(k0 + krow) * (HH * DD) + kcol,
                   Kl + ch * 512 + lane * 8);
      const int drow = ch * 8 + v_row_in;  // 0..127
      const int vcol = (v_slot ^ (drow & 7)) * 8;
      async_copy16(vbase + (size_t)drow * TT + k0 + vcol,
                   Vl + ch * 512 + lane * 8);
    }
    __syncthreads();                       // staging visible (vmcnt drained)

    // ---- QK^T: 4 key groups of 16 ----
    f32x4 sacc[4];
    #pragma unroll
    for (int kk = 0; kk < 4; kk++) sacc[kk] = f32x4{0.f, 0.f, 0.f, 0.f};
    #pragma unroll
    for (int ds = 0; ds < 4; ds++) {
      #pragma unroll
      for (int kk = 0; kk < 4; kk++) {
        const int key  = 16 * kk + lr;
        const int slot = (ds * 4 + quad) ^ lr;        // lr == key&15
        bf16x8 kf = *(const bf16x8*)&Kl[key * 128 + slot * 8];
        sacc[kk] = __builtin_amdgcn_mfma_f32_16x16x32_bf16(qf[ds], kf, sacc[kk], 0, 0, 0);
      }
    }

    // ---- online softmax over 64 keys ----
    const int qr = q0 + quad * 4;
    #pragma unroll
    for (int r = 0; r < 4; r++) {
      float v[4];
      #pragma unroll
      for (int kk = 0; kk < 4; kk++) {
        float x = sacc[kk][r] * sc;
        if (k0 + 16 * kk + lr > qr + r) x = -1e30f;   // causal mask
        v[kk] = x;
      }
      float mx = fmaxf(fmaxf(v[0], v[1]), fmaxf(v[2], v[3]));
      #pragma unroll
      for (int off = 1; off < 16; off <<= 1) mx = fmaxf(mx, __shfl_xor(mx, off, 64));
      float mnew  = fmaxf(m_r[r], mx);
      float alpha = __expf(m_r[r] - mnew);
      float e[4], ps = 0.f;
      #pragma unroll
      for (int kk = 0; kk < 4; kk++) { e[kk] = __expf(v[kk] - mnew); ps += e[kk]; }
      #pragma unroll
      for (int off = 1; off < 16; off <<= 1) ps += __shfl_xor(ps, off, 64);
      l_r[r] = l_r[r] * alpha + ps;
      m_r[r] = mnew;
      #pragma unroll
      for (int dc = 0; dc < 8; dc++) oacc[dc][r] *= alpha;
      #pragma unroll
      for (int kk = 0; kk < 4; kk++)
        Pl[wave][quad * 4 + r][kk * 16 + lr] = (bf16)e[kk];
    }
    __syncthreads();                       // P visible (C-layout -> A-layout)

    // ---- PV: P[16x64] @ V[64x128] ----
    bf16x8 pf0 = *(const bf16x8*)&Pl[wave][lr][quad * 8];
    bf16x8 pf1 = *(const bf16x8*)&Pl[wave][lr][32 + quad * 8];
    #pragma unroll
    for (int dc = 0; dc < 8; dc++) {
      const int d  = dc * 16 + lr;
      const int s0 = (quad)     ^ (lr & 7);
      const int s1 = (4 + quad) ^ (lr & 7);
      bf16x8 vf0 = *(const bf16x8*)&Vl[d * 64 + s0 * 8];
      bf16x8 vf1 = *(const bf16x8*)&Vl[d * 64 + s1 * 8];
      oacc[dc] = __builtin_amdgcn_mfma_f32_16x16x32_bf16(pf0, vf0, oacc[dc], 0, 0, 0);
      oacc[dc] = __builtin_amdgcn_mfma_f32_16x16x32_bf16(pf1, vf1, oacc[dc], 0, 0, 0);
    }
  }

  float inv[4];
  #pragma unroll
  for (int r = 0; r < 4; r++) inv[r] = 1.0f / l_r[r];
  bf16* aor = ao + ((size_t)(b * TT + q0 + quad * 4) * HH + h) * DD + lr;
  #pragma unroll
  for (int dc = 0; dc < 8; dc++)
    #pragma unroll
    for (int r = 0; r < 4; r++)
      aor[(size_t)r * HH * DD + dc * 16] = (bf16)(oacc[dc][r] * inv[r]);
}

// ---------------------------------------------------------------------------
// ws: Ab | Wt | qb | kb | vt | ao  (bf16, 32 MB each = 192 MB)
// ---------------------------------------------------------------------------
extern "C" void kernel_launch(void* const* d_in, const int* in_sizes, int n_in,
                              void* d_out, int out_size, void* d_ws, size_t ws_size,
                              hipStream_t stream)
{
  const float* hs   = (const float*)d_in[0];
  const float* sinp = (const float*)d_in[1];
  const float* cosp = (const float*)d_in[2];
  const float* Wq   = (const float*)d_in[4];
  const float* Wk   = (const float*)d_in[5];
  const float* Wv   = (const float*)d_in[6];
  const float* Wo   = (const float*)d_in[7];

  const size_t NE = (size_t)MM * CC;
  bf16* Ab = (bf16*)d_ws;
  bf16* Wt = Ab + NE;
  bf16* qb = Wt + NE;
  bf16* kb = qb + NE;
  bf16* vt = kb + NE;
  bf16* ao = vt + NE;

  dim3 gg(CC / 128, MM / 128), gb(256);
  dim3 gt(CC / 64, CC / 64);

  conv_k<<<NE / (256 * 8), 256, 0, stream>>>(hs, Ab);

  transpose_k<<<gt, gb, 0, stream>>>(Wq, Wt);
  gemm_k<0><<<gg, gb, 0, stream>>>(Ab, Wt, qb, sinp, cosp);

  transpose_k<<<gt, gb, 0, stream>>>(Wk, Wt);
  gemm_k<0><<<gg, gb, 0, stream>>>(Ab, Wt, kb, sinp, cosp);

  transpose_k<<<gt, gb, 0, stream>>>(Wv, Wt);
  gemm_k<1><<<gg, gb, 0, stream>>>(Ab, Wt, vt, sinp, cosp);

  attn_k<<<dim3(TT / 64, HH, BB), dim3(256), 0, stream>>>(qb, kb, vt, ao);

  transpose_k<<<gt, gb, 0, stream>>>(Wo, Wt);
  gemm_k<2><<<gg, gb, 0, stream>>>(ao, Wt, d_out, sinp, cosp);
}